// Round 2
// baseline (702.638 us; speedup 1.0000x reference)
//
#include <hip/hip_runtime.h>
#include <hip/hip_bf16.h>

#define HH 50
#define TT 1024
#define BT 16            // batch tile per block (MFMA M)
#define NB (2048 / BT)   // 128 blocks
#define CHUNK 256        // x staging chunk (timesteps)
#define XST 260          // x LDS row stride (floats)
#define HST 72           // h LDS row stride (bf16 elems)
#define PST 20           // p LDS row stride (floats), j-major

typedef __bf16 bf16x8 __attribute__((ext_vector_type(8)));
typedef float f32x4 __attribute__((ext_vector_type(4)));

union BF8 { bf16x8 v; unsigned short u[8]; };

__device__ __forceinline__ unsigned short f2bf(float f) {
    unsigned int u = __builtin_bit_cast(unsigned int, f);
    u += 0x7fffu + ((u >> 16) & 1u);   // RNE
    return (unsigned short)(u >> 16);
}
__device__ __forceinline__ float rcp_f(float x) { return __builtin_amdgcn_rcpf(x); }
__device__ __forceinline__ float sigm(float x) { return rcp_f(1.0f + __expf(-x)); }
__device__ __forceinline__ float tanh_f(float x) {
    return __builtin_fmaf(-2.0f, rcp_f(1.0f + __expf(2.0f * x)), 1.0f);
}

__global__ __launch_bounds__(512) void lstm_mfma_kernel(
    const float* __restrict__ x,
    const float* __restrict__ wih1, const float* __restrict__ whh1,
    const float* __restrict__ bih1, const float* __restrict__ bhh1,
    const float* __restrict__ wih2,
    const float* __restrict__ bih2, const float* __restrict__ bhh2,
    const float* __restrict__ fcw,  const float* __restrict__ fcb,
    float* __restrict__ out)
{
    __shared__ float xs[BT * XST];                 // 16.6 KB
    __shared__ unsigned short hb[2][BT * HST];     // 4.6 KB
    __shared__ float pb[64 * PST];                 // 5.1 KB, p = i*g, j-major
    __shared__ float h2s[BT * 52];                 // 3.3 KB

    const int tid  = threadIdx.x;
    const int wv   = tid >> 6;        // 0..7
    const int lane = tid & 63;
    const int l16  = lane & 15;
    const int quad = lane >> 4;
    const int jt   = wv & 3;          // j-tile
    const bool ig  = (wv < 4);        // waves 0-3: i,g ; waves 4-7: f,o + c-owner
    const int j    = jt * 16 + l16;   // padded gate sub-index 0..63
    const bool jv  = (j < HH);
    const int b0   = blockIdx.x * BT;

    // role gate types: IG -> t4 {0,2} (i,g); FO -> t4 {1,3} (f,o)
    const int t4A = ig ? 0 : 1;
    const int t4B = ig ? 2 : 3;

    // ---- persistent per-lane weights ----
    BF8 bwA[2], bwB[2];
    float wihA, wihB, biasA, biasB;
    {
        const int rowA = t4A * HH + j, rowB = t4B * HH + j;
        #pragma unroll
        for (int kk = 0; kk < 2; ++kk)
            #pragma unroll
            for (int e = 0; e < 8; ++e) {
                const int k = kk * 32 + quad * 8 + e;
                bwA[kk].u[e] = f2bf((jv && k < HH) ? whh1[rowA * HH + k] : 0.0f);
                bwB[kk].u[e] = f2bf((jv && k < HH) ? whh1[rowB * HH + k] : 0.0f);
            }
        wihA  = jv ? wih1[rowA] : 0.0f;
        wihB  = jv ? wih1[rowB] : 0.0f;
        biasA = jv ? (bih1[rowA] + bhh1[rowA]) : 0.0f;
        biasB = jv ? (bih1[rowB] + bhh1[rowB]) : 0.0f;
    }

    for (int i = tid; i < BT * HST; i += 512) hb[0][i] = 0;

    float c0 = 0.f, c1 = 0.f, c2 = 0.f, c3 = 0.f;   // FO waves own c
    unsigned short* cur = hb[0];
    unsigned short* nxt = hb[1];

    for (int t = 0; t < TT; ++t) {
        if ((t & (CHUNK - 1)) == 0) {
            for (int i = tid; i < BT * (CHUNK / 4); i += 512) {
                const int r = i >> 6, c4 = i & 63;
                const float4 xv = ((const float4*)x)[((b0 + r) * TT + t) / 4 + c4];
                *(float4*)&xs[r * XST + c4 * 4] = xv;
            }
            __syncthreads();   // also covers hb[0] zeroing at t==0
        }
        const int tc = t & (CHUNK - 1);

        // A-frags for h_t
        const bf16x8 a0 = *(const bf16x8*)&cur[l16 * HST + quad * 8];
        const bf16x8 a1 = *(const bf16x8*)&cur[l16 * HST + 32 + quad * 8];

        const float xv0 = xs[(quad * 4 + 0) * XST + tc];
        const float xv1 = xs[(quad * 4 + 1) * XST + tc];
        const float xv2 = xs[(quad * 4 + 2) * XST + tc];
        const float xv3 = xs[(quad * 4 + 3) * XST + tc];

        f32x4 accA, accB;
        accA[0] = __builtin_fmaf(xv0, wihA, biasA);
        accA[1] = __builtin_fmaf(xv1, wihA, biasA);
        accA[2] = __builtin_fmaf(xv2, wihA, biasA);
        accA[3] = __builtin_fmaf(xv3, wihA, biasA);
        accB[0] = __builtin_fmaf(xv0, wihB, biasB);
        accB[1] = __builtin_fmaf(xv1, wihB, biasB);
        accB[2] = __builtin_fmaf(xv2, wihB, biasB);
        accB[3] = __builtin_fmaf(xv3, wihB, biasB);

        accA = __builtin_amdgcn_mfma_f32_16x16x32_bf16(a0, bwA[0].v, accA, 0, 0, 0);
        accA = __builtin_amdgcn_mfma_f32_16x16x32_bf16(a1, bwA[1].v, accA, 0, 0, 0);
        accB = __builtin_amdgcn_mfma_f32_16x16x32_bf16(a0, bwB[0].v, accB, 0, 0, 0);
        accB = __builtin_amdgcn_mfma_f32_16x16x32_bf16(a1, bwB[1].v, accB, 0, 0, 0);

        float fr0, fr1, fr2, fr3, F0, F1, F2, F3;
        if (ig) {
            // p = i*g = (G-1) * rcp((1+A)(G+1));  A=e^{-a_i}, G=e^{2 a_g}
            float4 pv;
            {
                const float A = __expf(-accA[0]), G = __expf(2.0f * accB[0]);
                pv.x = (G - 1.0f) * rcp_f((1.0f + A) * (G + 1.0f));
            }
            {
                const float A = __expf(-accA[1]), G = __expf(2.0f * accB[1]);
                pv.y = (G - 1.0f) * rcp_f((1.0f + A) * (G + 1.0f));
            }
            {
                const float A = __expf(-accA[2]), G = __expf(2.0f * accB[2]);
                pv.z = (G - 1.0f) * rcp_f((1.0f + A) * (G + 1.0f));
            }
            {
                const float A = __expf(-accA[3]), G = __expf(2.0f * accB[3]);
                pv.w = (G - 1.0f) * rcp_f((1.0f + A) * (G + 1.0f));
            }
            *(float4*)&pb[j * PST + quad * 4] = pv;
        } else {
            // f = rcp(1+e^{-a_f}); F = e^{-a_o}
            fr0 = sigm(accA[0]); F0 = __expf(-accB[0]);
            fr1 = sigm(accA[1]); F1 = __expf(-accB[1]);
            fr2 = sigm(accA[2]); F2 = __expf(-accB[2]);
            fr3 = sigm(accA[3]); F3 = __expf(-accB[3]);
        }
        __syncthreads();   // p visible
        if (!ig) {
            const float4 pv = *(const float4*)&pb[j * PST + quad * 4];
            // h = o * tanh(c) = (E-1) * rcp((E+1)(1+F));  E = e^{2c}
            {
                c0 = __builtin_fmaf(fr0, c0, pv.x);
                const float E = __expf(2.0f * c0);
                nxt[(quad * 4 + 0) * HST + j] =
                    f2bf((E - 1.0f) * rcp_f((E + 1.0f) * (1.0f + F0)));
            }
            {
                c1 = __builtin_fmaf(fr1, c1, pv.y);
                const float E = __expf(2.0f * c1);
                nxt[(quad * 4 + 1) * HST + j] =
                    f2bf((E - 1.0f) * rcp_f((E + 1.0f) * (1.0f + F1)));
            }
            {
                c2 = __builtin_fmaf(fr2, c2, pv.z);
                const float E = __expf(2.0f * c2);
                nxt[(quad * 4 + 2) * HST + j] =
                    f2bf((E - 1.0f) * rcp_f((E + 1.0f) * (1.0f + F2)));
            }
            {
                c3 = __builtin_fmaf(fr3, c3, pv.w);
                const float E = __expf(2.0f * c3);
                nxt[(quad * 4 + 3) * HST + j] =
                    f2bf((E - 1.0f) * rcp_f((E + 1.0f) * (1.0f + F3)));
            }
        }
        __syncthreads();   // h visible
        unsigned short* tmp = cur; cur = nxt; nxt = tmp;
    }

    // ---- LSTM2 (one step from zero state), done by waves 0-3 as in round 1 ----
    if (ig) {
        BF8 bw2[4][2];
        float bias2S[4];
        #pragma unroll
        for (int t4 = 0; t4 < 4; ++t4) {
            const int row = t4 * HH + j;
            #pragma unroll
            for (int kk = 0; kk < 2; ++kk)
                #pragma unroll
                for (int e = 0; e < 8; ++e) {
                    const int k = kk * 32 + quad * 8 + e;
                    bw2[t4][kk].u[e] = f2bf((jv && k < HH) ? wih2[row * HH + k] : 0.0f);
                }
            bias2S[t4] = jv ? (bih2[row] + bhh2[row]) : 0.0f;
        }
        const bf16x8 a0 = *(const bf16x8*)&cur[l16 * HST + quad * 8];
        const bf16x8 a1 = *(const bf16x8*)&cur[l16 * HST + 32 + quad * 8];
        f32x4 acc2[4];
        #pragma unroll
        for (int t4 = 0; t4 < 4; ++t4) {
            acc2[t4][0] = bias2S[t4]; acc2[t4][1] = bias2S[t4];
            acc2[t4][2] = bias2S[t4]; acc2[t4][3] = bias2S[t4];
        }
        #pragma unroll
        for (int t4 = 0; t4 < 4; ++t4) {
            acc2[t4] = __builtin_amdgcn_mfma_f32_16x16x32_bf16(a0, bw2[t4][0].v, acc2[t4], 0, 0, 0);
            acc2[t4] = __builtin_amdgcn_mfma_f32_16x16x32_bf16(a1, bw2[t4][1].v, acc2[t4], 0, 0, 0);
        }
        #pragma unroll
        for (int r = 0; r < 4; ++r) {
            const float i2 = sigm(acc2[0][r]);
            const float g2 = tanh_f(acc2[2][r]);
            const float o2 = sigm(acc2[3][r]);
            const float cc = i2 * g2;           // f*c0 vanishes (c0 = 0)
            if (jv) h2s[(quad * 4 + r) * 52 + j] = o2 * tanh_f(cc);
        }
    }
    __syncthreads();

    // ---- FC: out[b] = h2[b] . fcW + fcb ----
    if (tid < 256) {
        const int b = tid >> 4, l = tid & 15;
        float p = 0.f;
        for (int jj = l; jj < HH; jj += 16)
            p = __builtin_fmaf(h2s[b * 52 + jj], fcw[jj], p);
        #pragma unroll
        for (int off = 8; off > 0; off >>= 1) p += __shfl_xor(p, off, 16);
        if (l == 0) out[b0 + b] = p + fcb[0];
    }
}

extern "C" void kernel_launch(void* const* d_in, const int* in_sizes, int n_in,
                              void* d_out, int out_size, void* d_ws, size_t ws_size,
                              hipStream_t stream) {
    lstm_mfma_kernel<<<NB, 512, 0, stream>>>(
        (const float*)d_in[0],
        (const float*)d_in[1], (const float*)d_in[2],
        (const float*)d_in[3], (const float*)d_in[4],
        (const float*)d_in[5],
        (const float*)d_in[7], (const float*)d_in[8],
        (const float*)d_in[9], (const float*)d_in[10],
        (float*)d_out);
}